// Round 22
// baseline (210.755 us; speedup 1.0000x reference)
//
#include <hip/hip_runtime.h>
#include <hip/hip_bf16.h>

#define N_NODES 100000
#define N_EDGES 1600000
#define D 128
#define BSZ 128                         // dst nodes per bucket
#define NBUCK 782                       // ceil(N_NODES / BSZ)
#define EPW 4096                        // edges per WG in scatter
#define NWG1 ((N_EDGES + EPW - 1) / EPW)  // 391
#define CAP 4096                        // LDS edge staging per bucket (mean 2048)
#define OTS 272                         // epilogue LDS tile row stride (bytes)

typedef unsigned int  uint4n  __attribute__((ext_vector_type(4)));
typedef float         float4n __attribute__((ext_vector_type(4)));
typedef _Float16      half8n  __attribute__((ext_vector_type(8)));
typedef _Float16      half4n  __attribute__((ext_vector_type(4)));

// swizzled LDS byte offset for element (row, kb): 256B per row, XOR bits 4-7
#define SWZ(row, kb) (((row) << 8) + ((kb) ^ (((row) & 15) << 4)))

// tanh(x) = 1 - 2/(exp2(2*log2e*x)+1); hw exp2+rcp, abs err ~2e-7.
__device__ __forceinline__ float fast_tanh(float x) {
    float t = __builtin_amdgcn_exp2f(x * 2.885390081777927f);
    return 1.0f - 2.0f * __builtin_amdgcn_rcpf(t + 1.0f);
}

// ---------------- W prep: Wt = fp16(W^T) swizzled image (32 blocks) ----------------
__global__ __launch_bounds__(256) void k_wprep(const float* __restrict__ W1,
                                               const float* __restrict__ W2,
                                               char* __restrict__ Wt) {
    const float* W = (blockIdx.x < 16) ? W1 : W2;
    char* dstp = Wt + ((blockIdx.x < 16) ? 0 : 32768);
    int t = (blockIdx.x & 15) * 256 + threadIdx.x;   // 0..4095
    int idx = t * 4;
    int k = idx >> 7, c = idx & 127;
    float4 wv = *(const float4*)&W[idx];
    *(_Float16*)(dstp + SWZ(c + 0, k * 2)) = (_Float16)wv.x;
    *(_Float16*)(dstp + SWZ(c + 1, k * 2)) = (_Float16)wv.y;
    *(_Float16*)(dstp + SWZ(c + 2, k * 2)) = (_Float16)wv.z;
    *(_Float16*)(dstp + SWZ(c + 3, k * 2)) = (_Float16)wv.w;
}

// ---------------- fused: block-local bucket sort (blocks 0..NWG1-1) || GEMM layer 1 ----------
// Scatter role: LDS hist of own 4096 edges -> in-LDS exclusive scan -> write cntM/loffM
// matrices + bucket-grouped records into OWN dense staging region (no global atomics).
// Record: (src<<8 | dst&127, weight) = 8B; src<<8 IS the byte offset of H row.
// GEMM role: H[n x 128](fp16) = X_f32 @ W1, staged fp16 LDS, MFMA 16x16x32.
__global__ __launch_bounds__(256) void k_scat_gemm(const int* __restrict__ src,
                                                   const int* __restrict__ dst,
                                                   const float* __restrict__ ew,
                                                   int2* __restrict__ staging,
                                                   int* __restrict__ cntM,
                                                   int* __restrict__ loffM,
                                                   const float* __restrict__ Xf,
                                                   const char* __restrict__ Wt,
                                                   _Float16* __restrict__ H, int n) {
    __shared__ char smem[17408];
    int tid = threadIdx.x;

    if (blockIdx.x < NWG1) {
        // ---- block-local sort role ----
        int* h   = (int*)smem;            // [NBUCK]
        int* cur = h + NBUCK;             // [NBUCK]
        int* tmp = cur + NBUCK;           // [256]
        int blk  = blockIdx.x;
        for (int i = tid; i < NBUCK; i += 256) h[i] = 0;
        __syncthreads();
        int base = blk * EPW;
        int end  = min(base + EPW, N_EDGES);
        {
            int i = base + tid;
            for (; i + 768 < end; i += 1024) {     // 4 loads in flight
                int d0 = dst[i], d1 = dst[i + 256], d2 = dst[i + 512], d3 = dst[i + 768];
                atomicAdd(&h[d0 >> 7], 1);
                atomicAdd(&h[d1 >> 7], 1);
                atomicAdd(&h[d2 >> 7], 1);
                atomicAdd(&h[d3 >> 7], 1);
            }
            for (; i < end; i += 256)
                atomicAdd(&h[dst[i] >> 7], 1);
        }
        __syncthreads();
        // exclusive scan of h[0..NBUCK) -> cur; write matrices
        int carry = 0;
        for (int c = 0; c < 4; c++) {             // 4*256 = 1024 >= NBUCK
            int i = c * 256 + tid;
            int v = (i < NBUCK) ? h[i] : 0;
            tmp[tid] = v;
            __syncthreads();
            int run = v;
            for (int off = 1; off < 256; off <<= 1) {
                int t = (tid >= off) ? tmp[tid - off] : 0;
                __syncthreads();
                run += t;
                tmp[tid] = run;
                __syncthreads();
            }
            int excl = carry + run - v;
            if (i < NBUCK) {
                cur[i] = excl;
                cntM[blk * NBUCK + i]  = v;
                loffM[blk * NBUCK + i] = excl;
            }
            int tot = tmp[255];
            __syncthreads();
            carry += tot;
        }
        __syncthreads();
        // place records bucket-grouped into own staging region (L2-resident 32KB)
        {
            int2* sg = staging + (size_t)blk * EPW;
            int i = base + tid;
            for (; i + 768 < end; i += 1024) {     // batched loads, 4 indep chains
                int d0 = dst[i], d1 = dst[i + 256], d2 = dst[i + 512], d3 = dst[i + 768];
                int s0 = src[i], s1 = src[i + 256], s2 = src[i + 512], s3 = src[i + 768];
                float w0 = ew[i], w1 = ew[i + 256], w2 = ew[i + 512], w3 = ew[i + 768];
                int p0 = atomicAdd(&cur[d0 >> 7], 1);
                int p1 = atomicAdd(&cur[d1 >> 7], 1);
                int p2 = atomicAdd(&cur[d2 >> 7], 1);
                int p3 = atomicAdd(&cur[d3 >> 7], 1);
                sg[p0] = make_int2((s0 << 8) | (d0 & 127), __float_as_int(w0));
                sg[p1] = make_int2((s1 << 8) | (d1 & 127), __float_as_int(w1));
                sg[p2] = make_int2((s2 << 8) | (d2 & 127), __float_as_int(w2));
                sg[p3] = make_int2((s3 << 8) | (d3 & 127), __float_as_int(w3));
            }
            for (; i < end; i += 256) {
                int d = dst[i];
                int p = atomicAdd(&cur[d >> 7], 1);
                sg[p] = make_int2((src[i] << 8) | (d & 127), __float_as_int(ew[i]));
            }
        }
        return;
    }

    // ---- GEMM layer-1 role ----
    char* sA = smem;
    int lane = tid & 63, w = tid >> 6;
    int rows0 = (blockIdx.x - NWG1) * 64;

    int rb2 = (w >> 1) * 32;     // wave row base within slab (0/32)
    int cb = (w & 1) * 64;       // wave col base (0/64)
    int lr = lane & 15;          // frag row/col within tile
    int kg = (lane >> 4) * 16;   // k-group byte offset

    #pragma unroll
    for (int rep = 0; rep < 8; rep++) {
        int ef = rep * 1024 + tid * 4;
        int r = ef >> 7, c = ef & 127;
        int rg = rows0 + r;
        float4 xv = make_float4(0.f, 0.f, 0.f, 0.f);
        if (rg < n) xv = *(const float4*)(Xf + (size_t)rg * 128 + c);
        half4n hv;
        hv[0] = (_Float16)xv.x; hv[1] = (_Float16)xv.y;
        hv[2] = (_Float16)xv.z; hv[3] = (_Float16)xv.w;
        *(half4n*)(sA + SWZ(r, c * 2)) = hv;
    }
    __syncthreads();

    float4n acc[2][4] = {};
    #pragma unroll
    for (int ks = 0; ks < 4; ks++) {
        half8n bwk[4];
        #pragma unroll
        for (int ct = 0; ct < 4; ct++)
            bwk[ct] = *(const half8n*)(Wt + SWZ(cb + ct * 16 + lr, ks * 64 + kg));
        half8n af[2];
        #pragma unroll
        for (int rt = 0; rt < 2; rt++)
            af[rt] = *(const half8n*)(sA + SWZ(rb2 + rt * 16 + lr, ks * 64 + kg));
        #pragma unroll
        for (int rt = 0; rt < 2; rt++)
            #pragma unroll
            for (int ct = 0; ct < 4; ct++)
                acc[rt][ct] = __builtin_amdgcn_mfma_f32_16x16x32_f16(af[rt], bwk[ct], acc[rt][ct], 0, 0, 0);
    }

    __syncthreads();                              // sA dead, reuse as OT
    char* OT = smem;
    int rloc = rb2 + (lane >> 4) * 4;
    #pragma unroll
    for (int rt = 0; rt < 2; rt++) {
        #pragma unroll
        for (int ct = 0; ct < 4; ct++) {
            int col = cb + ct * 16 + lr;
            #pragma unroll
            for (int r = 0; r < 4; r++)
                *(_Float16*)(OT + (rloc + rt * 16 + r) * OTS + col * 2) = (_Float16)acc[rt][ct][r];
        }
    }
    __syncthreads();
    #pragma unroll
    for (int rep = 0; rep < 4; rep++) {
        int ef = rep * 2048 + tid * 8;
        int r = ef >> 7, c = ef & 127;
        int rg = rows0 + r;
        if (rg < n) {
            half8n v = *(const half8n*)(OT + r * OTS + c * 2);
            *(half8n*)&H[(size_t)rg * 128 + c] = v;
        }
    }
}

// ---------------- column sums of cntM -> bcnt (plain writes, no memset needed) ------------
__global__ __launch_bounds__(256) void k_sumcol(const int* __restrict__ cntM,
                                                int* __restrict__ bcnt) {
    int b = blockIdx.x * 256 + threadIdx.x;
    if (b >= NBUCK) return;
    int s = 0;
    int blk = 0;
    for (; blk + 4 <= NWG1; blk += 4) {
        int a0 = cntM[(size_t)(blk + 0) * NBUCK + b];
        int a1 = cntM[(size_t)(blk + 1) * NBUCK + b];
        int a2 = cntM[(size_t)(blk + 2) * NBUCK + b];
        int a3 = cntM[(size_t)(blk + 3) * NBUCK + b];
        s += a0 + a1 + a2 + a3;
    }
    for (; blk < NWG1; blk++) s += cntM[(size_t)blk * NBUCK + b];
    bcnt[b] = s;
}

// Single-block exclusive scan over NBUCK counts -> boff.
__global__ void k_scanN(const int* __restrict__ bcnt, int* __restrict__ boff) {
    __shared__ int tmp[256];
    int tid = threadIdx.x;
    int carry = 0;
    for (int c = 0; c < (NBUCK + 255) / 256; c++) {
        int i = c * 256 + tid;
        int v = (i < NBUCK) ? bcnt[i] : 0;
        tmp[tid] = v;
        __syncthreads();
        int run = v;
        for (int off = 1; off < 256; off <<= 1) {
            int t = (tid >= off) ? tmp[tid - off] : 0;
            __syncthreads();
            run += t;
            tmp[tid] = run;
            __syncthreads();
        }
        int excl = carry + run - v;
        if (i < NBUCK) boff[i] = excl;
        int tot = tmp[255];
        __syncthreads();
        carry += tot;
    }
    if (tid == 0) boff[NBUCK] = N_EDGES;
}

// ---------------- per-bucket gather (391 runs) + counting sort + rowptr ----------------
__global__ __launch_bounds__(512) void k_sortb(const int2* __restrict__ staging,
                                               const int* __restrict__ cntM,
                                               const int* __restrict__ loffM,
                                               const int* __restrict__ boff,
                                               int2* __restrict__ ebuf,
                                               int* __restrict__ rowptr) {
    __shared__ int2 se[CAP];
    __shared__ int rcs[512];     // inclusive sums of per-blk counts
    __shared__ int rco[512];     // original per-blk counts
    __shared__ int lfs[NWG1];    // per-blk local offsets
    __shared__ int cnt2[BSZ];
    __shared__ int cur2[BSZ];
    int tid = threadIdx.x;
    int b   = blockIdx.x;
    int e0 = boff[b], e1 = boff[b + 1];
    int m  = e1 - e0;
    {
        int v = (tid < NWG1) ? cntM[(size_t)tid * NBUCK + b] : 0;
        rcs[tid] = v;
        rco[tid] = v;
        if (tid < NWG1) lfs[tid] = loffM[(size_t)tid * NBUCK + b];
        if (tid < BSZ) cnt2[tid] = 0;
    }
    __syncthreads();
    // inclusive scan over 512 (Hillis-Steele)
    for (int off = 1; off < 512; off <<= 1) {
        int t = (tid >= off) ? rcs[tid - off] : 0;
        __syncthreads();
        rcs[tid] += t;
        __syncthreads();
    }
    // gather + histogram
    for (int i = tid; i < m; i += 512) {
        int lo = 0, hi = NWG1 - 1;                // first blk with rcs[blk] > i
        while (lo < hi) { int mid = (lo + hi) >> 1; if (rcs[mid] > i) hi = mid; else lo = mid + 1; }
        int blk = lo;
        int within = i - (rcs[blk] - rco[blk]);
        int2 rec = staging[(size_t)blk * EPW + lfs[blk] + within];
        if (i < CAP) se[i] = rec;                 // m <= CAP statistically always
        atomicAdd(&cnt2[rec.x & (BSZ - 1)], 1);
    }
    __syncthreads();
    if (tid < 64) {                               // wave-0 shfl scan of 128 counts
        int a  = cnt2[tid * 2], bq = cnt2[tid * 2 + 1];
        int s  = a + bq;
        int incl = s;
        #pragma unroll
        for (int off = 1; off < 64; off <<= 1) {
            int t = __shfl_up(incl, off, 64);
            if (tid >= off) incl += t;
        }
        int ex = incl - s;                        // exclusive prefix of this pair
        cur2[tid * 2]     = ex;
        cur2[tid * 2 + 1] = ex + a;
        int node = b * BSZ + tid * 2;
        if (node     <= N_NODES) rowptr[node]     = e0 + ex;
        if (node + 1 <= N_NODES) rowptr[node + 1] = e0 + ex + a;
    }
    __syncthreads();
    // place
    for (int i = tid; i < m; i += 512) {
        int2 rec;
        if (i < CAP) rec = se[i];
        else {                                    // rare overflow path: re-gather
            int lo = 0, hi = NWG1 - 1;
            while (lo < hi) { int mid = (lo + hi) >> 1; if (rcs[mid] > i) hi = mid; else lo = mid + 1; }
            int blk = lo;
            rec = staging[(size_t)blk * EPW + lfs[blk] + (i - (rcs[blk] - rco[blk]))];
        }
        int p = atomicAdd(&cur2[rec.x & (BSZ - 1)], 1);
        ebuf[e0 + p] = rec;
    }
}

// ---------------- GEMM (layer 2, fp16 in): staged LDS path ----------------
__global__ __launch_bounds__(256) void k_gemm2(const _Float16* __restrict__ Xh,
                                               const char* __restrict__ Wt,
                                               _Float16* __restrict__ H, int n) {
    __shared__ char smem[17408];
    char* sA = smem;
    int tid  = threadIdx.x;
    int lane = tid & 63, w = tid >> 6;
    int rows0 = blockIdx.x * 64;

    int rb = (w >> 1) * 32;
    int cb = (w & 1) * 64;
    int lr = lane & 15;
    int kg = (lane >> 4) * 16;

    #pragma unroll
    for (int rep = 0; rep < 4; rep++) {
        int ef = rep * 2048 + tid * 8;
        int r = ef >> 7, c = ef & 127;
        int rg = rows0 + r;
        half8n v = half8n(0);
        if (rg < n) v = *(const half8n*)(Xh + (size_t)rg * 128 + c);
        *(half8n*)(sA + SWZ(r, c * 2)) = v;
    }
    __syncthreads();

    float4n acc[2][4] = {};
    #pragma unroll
    for (int ks = 0; ks < 4; ks++) {
        half8n bwk[4];
        #pragma unroll
        for (int ct = 0; ct < 4; ct++)
            bwk[ct] = *(const half8n*)(Wt + SWZ(cb + ct * 16 + lr, ks * 64 + kg));
        half8n af[2];
        #pragma unroll
        for (int rt = 0; rt < 2; rt++)
            af[rt] = *(const half8n*)(sA + SWZ(rb + rt * 16 + lr, ks * 64 + kg));
        #pragma unroll
        for (int rt = 0; rt < 2; rt++)
            #pragma unroll
            for (int ct = 0; ct < 4; ct++)
                acc[rt][ct] = __builtin_amdgcn_mfma_f32_16x16x32_f16(af[rt], bwk[ct], acc[rt][ct], 0, 0, 0);
    }

    __syncthreads();
    char* OT = smem;
    int rloc = rb + (lane >> 4) * 4;
    #pragma unroll
    for (int rt = 0; rt < 2; rt++) {
        #pragma unroll
        for (int ct = 0; ct < 4; ct++) {
            int col = cb + ct * 16 + lr;
            #pragma unroll
            for (int r = 0; r < 4; r++)
                *(_Float16*)(OT + (rloc + rt * 16 + r) * OTS + col * 2) = (_Float16)acc[rt][ct][r];
        }
    }
    __syncthreads();
    #pragma unroll
    for (int rep = 0; rep < 4; rep++) {
        int ef = rep * 2048 + tid * 8;
        int r = ef >> 7, c = ef & 127;
        int rg = rows0 + r;
        if (rg < n) {
            half8n v = *(const half8n*)(OT + r * OTS + c * 2);
            *(half8n*)&H[(size_t)rg * 128 + c] = v;
        }
    }
}

// ---------------- Aggregation: out[n] = tanh(sum_e w_e * H[src_e]) ----------------
// FOUR nodes per wave (16-lane group per node). Inner loop keeps FOUR gathers
// in flight: load 4 edge records first, then issue 4 H-row gathers, then FMAs.
template<bool OUTF16>
__global__ __launch_bounds__(256) void k_agg(const _Float16* __restrict__ H,
                                             const int* __restrict__ rowptr,
                                             const int2* __restrict__ ebuf,
                                             void* __restrict__ outv, int n) {
    int wv   = (blockIdx.x * 256 + threadIdx.x) >> 6;   // global wave index
    int lane = threadIdx.x & 63;
    int g = lane >> 4;                 // node slot within wave (0..3)
    int c = lane & 15;                 // columns c*8 .. c*8+7 (16B of the row)
    int node = wv * 4 + g;
    if (node >= n) return;
    const char* Hc = (const char*)H + (c << 4);   // per-lane column base
    int e0 = rowptr[node], e1 = rowptr[node + 1];
    float acc[8] = {};
    int e = e0;
    for (; e + 4 <= e1; e += 4) {                 // 4 gathers in flight
        int2 d0 = ebuf[e];
        int2 d1 = ebuf[e + 1];
        int2 d2 = ebuf[e + 2];
        int2 d3 = ebuf[e + 3];
        half8n v0 = *(const half8n*)(Hc + (size_t)((unsigned)d0.x & 0xFFFFFF00u));
        half8n v1 = *(const half8n*)(Hc + (size_t)((unsigned)d1.x & 0xFFFFFF00u));
        half8n v2 = *(const half8n*)(Hc + (size_t)((unsigned)d2.x & 0xFFFFFF00u));
        half8n v3 = *(const half8n*)(Hc + (size_t)((unsigned)d3.x & 0xFFFFFF00u));
        float w0 = __int_as_float(d0.y);
        float w1 = __int_as_float(d1.y);
        float w2 = __int_as_float(d2.y);
        float w3 = __int_as_float(d3.y);
        #pragma unroll
        for (int j = 0; j < 8; j++) acc[j] = __builtin_fmaf((float)v0[j], w0, acc[j]);
        #pragma unroll
        for (int j = 0; j < 8; j++) acc[j] = __builtin_fmaf((float)v1[j], w1, acc[j]);
        #pragma unroll
        for (int j = 0; j < 8; j++) acc[j] = __builtin_fmaf((float)v2[j], w2, acc[j]);
        #pragma unroll
        for (int j = 0; j < 8; j++) acc[j] = __builtin_fmaf((float)v3[j], w3, acc[j]);
    }
    for (; e < e1; ++e) {
        int2 ed = ebuf[e];
        half8n v = *(const half8n*)(Hc + (size_t)((unsigned)ed.x & 0xFFFFFF00u));
        float w = __int_as_float(ed.y);
        #pragma unroll
        for (int j = 0; j < 8; j++) acc[j] = __builtin_fmaf((float)v[j], w, acc[j]);
    }
    if (OUTF16) {
        half8n hv;
        #pragma unroll
        for (int j = 0; j < 8; j++) hv[j] = (_Float16)fast_tanh(acc[j]);
        // plain store: act1 is re-read by the next GEMM, keep it cache-resident
        *(uint4n*)((_Float16*)outv + (size_t)node * 128 + c * 8) = *(uint4n*)&hv;
    } else {
        float* op = (float*)outv + (size_t)node * 128 + c * 8;
        float4n o0, o1;
        o0.x = fast_tanh(acc[0]); o0.y = fast_tanh(acc[1]);
        o0.z = fast_tanh(acc[2]); o0.w = fast_tanh(acc[3]);
        o1.x = fast_tanh(acc[4]); o1.y = fast_tanh(acc[5]);
        o1.z = fast_tanh(acc[6]); o1.w = fast_tanh(acc[7]);
        __builtin_nontemporal_store(o0, (float4n*)op);
        __builtin_nontemporal_store(o1, (float4n*)(op + 4));
    }
}

// ---------------- launch ----------------

extern "C" void kernel_launch(void* const* d_in, const int* in_sizes, int n_in,
                              void* d_out, int out_size, void* d_ws, size_t ws_size,
                              hipStream_t stream) {
    const float* x    = (const float*)d_in[0];
    const int*   esrc = (const int*)d_in[1];
    const int*   edst = (const int*)d_in[2];
    const float* ew   = (const float*)d_in[3];
    const float* W1   = (const float*)d_in[4];
    const float* W2   = (const float*)d_in[5];
    float* out = (float*)d_out;

    // Workspace layout (~64.6 MB):
    _Float16* hbuf = (_Float16*)d_ws;                      // N*D fp16 (25.6 MB)
    _Float16* act1 = hbuf + (size_t)N_NODES * D;           // N*D fp16 (25.6 MB)
    // staging + matrices live INSIDE the act1 region (consumed by sortb before agg1 writes):
    int2* staging  = (int2*)act1;                          // NWG1*EPW int2 (12.81 MB)
    int*  cntM     = (int*)(staging + (size_t)NWG1 * EPW); // NWG1*NBUCK (1.22 MB)
    int*  loffM    = cntM + (size_t)NWG1 * NBUCK;          // NWG1*NBUCK (1.22 MB)
    int2* ebuf     = (int2*)(act1 + (size_t)N_NODES * D);  // E int2 (12.8 MB)
    int*  bcnt     = (int*)(ebuf + N_EDGES);               // NBUCK
    int*  boff     = bcnt + NBUCK;                         // NBUCK+1
    int*  rowptr   = boff + (NBUCK + 2);                   // N+1 ints (0.4 MB)
    char* Wt       = (char*)(rowptr + N_NODES + 8);        // 64 KB (two 32KB blobs)
    (void)ws_size; (void)in_sizes; (void)n_in; (void)out_size;

    int gemm_blocks = (N_NODES + 63) / 64;                  // 1563
    int agg_blocks  = (N_NODES + 15) / 16;                  // 4 waves/block, 4 nodes/wave

    // --- W prep, then CSR block-local sort overlapped with GEMM-1 ---
    k_wprep<<<32, 256, 0, stream>>>(W1, W2, Wt);
    k_scat_gemm<<<NWG1 + gemm_blocks, 256, 0, stream>>>(esrc, edst, ew,
                                                        staging, cntM, loffM,
                                                        x, Wt, hbuf, N_NODES);
    k_sumcol<<<(NBUCK + 255) / 256, 256, 0, stream>>>(cntM, bcnt);
    k_scanN<<<1, 256, 0, stream>>>(bcnt, boff);
    k_sortb<<<NBUCK, 512, 0, stream>>>(staging, cntM, loffM, boff, ebuf, rowptr);

    // --- layer 1 aggregation (overwrites act1/staging region — staging already consumed) ---
    k_agg<true><<<agg_blocks, 256, 0, stream>>>(hbuf, rowptr, ebuf, act1, N_NODES);
    // --- layer 2 ---
    k_gemm2<<<gemm_blocks, 256, 0, stream>>>(act1, Wt + 32768, hbuf, N_NODES);
    k_agg<false><<<agg_blocks, 256, 0, stream>>>(hbuf, rowptr, ebuf, out, N_NODES);
}